// Round 1
// baseline (148.748 us; speedup 1.0000x reference)
//
#include <hip/hip_runtime.h>
#include <hip/hip_bf16.h>
#include <cmath>

#define NROWS 32768
#define DIN   1024
#define DOUT  1024
#define BM    64
#define BK    32
#define MAXNORM 0.996f   // (1 - 4e-3)/sqrt(c), c = 1
#define XPAD  40         // padded Xt row length in bf16 elems (80 B rows -> 2-way banks)

typedef __attribute__((ext_vector_type(8))) __bf16 bf16x8;
typedef __attribute__((ext_vector_type(4))) __bf16 bf16x4;
typedef __attribute__((ext_vector_type(4))) float  f32x4;

__device__ __forceinline__ void gload16(const void* g, void* l) {
    __builtin_amdgcn_global_load_lds(
        (const __attribute__((address_space(1))) void*)g,
        (__attribute__((address_space(3))) void*)l, 16, 0, 0);
}

__device__ __forceinline__ unsigned pack2bf(float a, float b) {
    union { unsigned u; __bf16 h[2]; } p;
    p.h[0] = (__bf16)a; p.h[1] = (__bf16)b;
    return p.u;
}

__global__ void conv_w_kernel(const float* __restrict__ Wf, __bf16* __restrict__ Wb) {
    int i = (blockIdx.x * blockDim.x + threadIdx.x) * 4;
    f32x4 v = *(const f32x4*)(Wf + i);
    bf16x4 o;
    o[0] = (__bf16)v[0]; o[1] = (__bf16)v[1];
    o[2] = (__bf16)v[2]; o[3] = (__bf16)v[3];
    *(bf16x4*)(Wb + i) = o;
}

// Fused: bf16 MFMA GEMM (x @ W^T) + hyperbolic epilogue.
// out[m][n] = F1[m]*mx[m][n] + F2[m]*hb[n], F1/F2 from row reductions.
template<bool WBF>
__global__ __launch_bounds__(1024, 4) void hyp_kernel(
    const float* __restrict__ X,
    const float* __restrict__ Wf,
    const __bf16* __restrict__ Wb,
    const float* __restrict__ bias,
    float* __restrict__ out)
{
    __shared__ __align__(16) __bf16 Wt[2][DOUT * BK];   // [n][k] linear, 2x64KB
    __shared__ __align__(16) __bf16 Xt[2][BM * XPAD];   // padded rows, 2x5KB
    __shared__ float hbs[DOUT];
    __shared__ float redq[2][32][8];
    __shared__ float redd[2][32][8];
    __shared__ float xsqs[BM];
    __shared__ float fco[BM][2];
    __shared__ float bred[16];

    const int tid  = threadIdx.x;
    const int lane = tid & 63;
    const int wid  = tid >> 6;       // 0..15
    const int wm   = wid >> 3;       // 0..1 : row-group of 32
    const int wn   = wid & 7;        // 0..7 : col-group of 128
    const int row0 = blockIdx.x * BM;
    const int l15  = lane & 15;
    const int l4   = lane >> 4;

    // x staging assignment: thread -> (row, k-pair)
    const int xr  = tid >> 4;        // 0..63
    const int xk2 = tid & 15;        // 0..15 -> k = 2*xk2
    const float* xp = X + (size_t)(row0 + xr) * DIN + xk2 * 2;
    float xsq = 0.f;

    f32x4 acc[2][8];
    #pragma unroll
    for (int i = 0; i < 2; i++)
        #pragma unroll
        for (int j = 0; j < 8; j++)
            acc[i][j] = (f32x4){0.f, 0.f, 0.f, 0.f};

    auto STAGE = [&](int buf, int kt) {
        if (kt < DIN / BK) {
            if constexpr (WBF) {
                #pragma unroll
                for (int j = 0; j < 4; j++) {
                    int c = (j << 10) + tid;            // chunk id, 16 B each
                    int n = c >> 2, k16 = c & 3;
                    const __bf16* g = Wb + ((size_t)n * DIN + kt * BK + k16 * 8);
                    // wave-uniform LDS base; HW scatters base + lane*16
                    char* ldsb = (char*)(&Wt[buf][0]) + (((j << 10) + (wid << 6)) << 4);
                    gload16(g, ldsb);
                }
            } else {
                #pragma unroll
                for (int j = 0; j < 8; j++) {
                    int c = (j << 10) + tid;
                    int n = c >> 3, k4 = c & 7;
                    f32x4 wv = *(const f32x4*)(Wf + (size_t)n * DIN + kt * BK + k4 * 4);
                    uint2 pk;
                    pk.x = pack2bf(wv[0], wv[1]);
                    pk.y = pack2bf(wv[2], wv[3]);
                    *(uint2*)((char*)(&Wt[buf][0]) + n * (BK * 2) + k4 * 8) = pk;
                }
            }
            float2 xv = *(const float2*)(xp + kt * BK);
            xsq += xv.x * xv.x + xv.y * xv.y;           // fused ||x_row||^2 (fp32 source)
            *(unsigned*)((char*)(&Xt[buf][0]) + xr * (XPAD * 2) + xk2 * 4) =
                pack2bf(xv.x, xv.y);
        }
    };

    // ---- prologue: issue tile 0, overlap its latency with hyp-bias compute ----
    STAGE(0, 0);

    float bv = bias[tid];
    float bs = bv * bv;
    #pragma unroll
    for (int m = 1; m < 64; m <<= 1) bs += __shfl_xor(bs, m);
    if (lane == 0) bred[wid] = bs;
    __syncthreads();
    float tot = 0.f;
    #pragma unroll
    for (int i = 0; i < 16; i++) tot += bred[i];
    const float bnorm = sqrtf(fmaxf(tot, 1e-15f));      // safe_norm(bias)
    const float bth   = tanhf(bnorm);                   // expmap0 factor * bnorm
    float hbv = bth / bnorm * bv;
    float hn  = bth;                                    // ||hb|| before project
    if (hn > MAXNORM) { hbv *= MAXNORM / hn; hn = MAXNORM; }
    hbs[tid] = hbv;
    const float y2c = hn * hn;                          // ||hyp_bias||^2
    __syncthreads();

    // ---- K loop: double-buffered, 1 barrier per step, stage-before-compute ----
    int cur = 0;
    for (int kt = 0; kt < DIN / BK; kt++) {
        STAGE(cur ^ 1, kt + 1);
        const char* xb = (const char*)(&Xt[cur][0]);
        const char* wb = (const char*)(&Wt[cur][0]);
        bf16x8 a0 = *(const bf16x8*)(xb + (wm * 32 +      l15) * (XPAD * 2) + l4 * 16);
        bf16x8 a1 = *(const bf16x8*)(xb + (wm * 32 + 16 + l15) * (XPAD * 2) + l4 * 16);
        #pragma unroll
        for (int nt = 0; nt < 8; nt++) {
            bf16x8 b = *(const bf16x8*)(wb + (wn * 128 + nt * 16 + l15) * (BK * 2) + l4 * 16);
            acc[0][nt] = __builtin_amdgcn_mfma_f32_16x16x32_bf16(a0, b, acc[0][nt], 0, 0, 0);
            acc[1][nt] = __builtin_amdgcn_mfma_f32_16x16x32_bf16(a1, b, acc[1][nt], 0, 0, 0);
        }
        __syncthreads();
        cur ^= 1;
    }

    // ---- row reductions ----
    // ||x_row||^2 : 16 staging threads per row share l4 group -> shfl over low 4 bits
    float xs = xsq;
    #pragma unroll
    for (int m = 1; m < 16; m <<= 1) xs += __shfl_xor(xs, m);
    if (xk2 == 0) xsqs[xr] = xs;

    float hv[8];
    #pragma unroll
    for (int nt = 0; nt < 8; nt++) hv[nt] = hbs[wn * 128 + nt * 16 + l15];

    #pragma unroll
    for (int mt = 0; mt < 2; mt++) {
        #pragma unroll
        for (int r = 0; r < 4; r++) {
            float s = 0.f, d = 0.f;
            #pragma unroll
            for (int nt = 0; nt < 8; nt++) {
                float v = acc[mt][nt][r];
                s += v * v;
                d += v * hv[nt];
            }
            // lanes with same l4 hold the same rows (cols vary) -> reduce low 4 bits
            #pragma unroll
            for (int m = 1; m < 16; m <<= 1) {
                s += __shfl_xor(s, m);
                d += __shfl_xor(d, m);
            }
            if (l15 == 0) {
                int rl = mt * 16 + l4 * 4 + r;
                redq[wm][rl][wn] = s;
                redd[wm][rl][wn] = d;
            }
        }
    }
    __syncthreads();

    // ---- per-row scalars (64 threads) ----
    if (tid < BM) {
        int r = tid;
        float sq = 0.f, dt = 0.f;
        #pragma unroll
        for (int w = 0; w < 8; w++) {
            sq += redq[r >> 5][r & 31][w];
            dt += redd[r >> 5][r & 31][w];
        }
        float sx     = xsqs[r];
        float xnorm  = sqrtf(fmaxf(sx, 1e-15f));
        float mxnorm = sqrtf(fmaxf(sq, 1e-15f));
        float u  = fminf(xnorm, 1.f - 1e-5f);           // artanh clip
        float tv = tanhf(mxnorm / xnorm * atanhf(u));   // ||res||
        float rn = fminf(tv, MAXNORM);                  // project(res) norm
        float s  = rn / mxnorm;                         // res_p = s * mx
        float xy = s * dt;                              // <res_p, hb>
        float x2 = rn * rn;
        float Am = 1.f + 2.f * xy + y2c;
        float Bm = 1.f - x2;
        float Dm = fmaxf(1.f + 2.f * xy + x2 * y2c, 1e-15f);
        float g1 = Am * s / Dm;                         // o = g1*mx + g2*hb
        float g2 = Bm / Dm;
        float osq   = g1 * g1 * sq + 2.f * g1 * g2 * dt + g2 * g2 * y2c;
        float onorm = sqrtf(fmaxf(osq, 1e-15f));
        float psc   = onorm > MAXNORM ? MAXNORM / onorm : 1.f;  // final project
        fco[r][0] = g1 * psc;
        fco[r][1] = g2 * psc;
    }
    __syncthreads();

    // ---- epilogue write ----
    #pragma unroll
    for (int mt = 0; mt < 2; mt++) {
        #pragma unroll
        for (int r = 0; r < 4; r++) {
            int rl = wm * 32 + mt * 16 + l4 * 4 + r;
            float F1 = fco[rl][0], F2 = fco[rl][1];
            float* orow = out + (size_t)(row0 + rl) * DOUT;
            #pragma unroll
            for (int nt = 0; nt < 8; nt++) {
                int n = wn * 128 + nt * 16 + l15;
                orow[n] = F1 * acc[mt][nt][r] + F2 * hv[nt];
            }
        }
    }
}

extern "C" void kernel_launch(void* const* d_in, const int* in_sizes, int n_in,
                              void* d_out, int out_size, void* d_ws, size_t ws_size,
                              hipStream_t stream) {
    const float* X    = (const float*)d_in[0];
    const float* W    = (const float*)d_in[1];
    const float* bias = (const float*)d_in[2];
    float* out = (float*)d_out;

    const size_t wb_bytes = (size_t)DOUT * DIN * 2;
    if (ws_size >= wb_bytes) {
        __bf16* Wb = (__bf16*)d_ws;
        conv_w_kernel<<<dim3(DOUT * DIN / 1024), dim3(256), 0, stream>>>(W, Wb);
        hyp_kernel<true><<<dim3(NROWS / BM), dim3(1024), 0, stream>>>(X, W, Wb, bias, out);
    } else {
        hyp_kernel<false><<<dim3(NROWS / BM), dim3(1024), 0, stream>>>(X, W, nullptr, bias, out);
    }
}

// Round 2
// 135.427 us; speedup vs baseline: 1.0984x; 1.0984x over previous
//
#include <hip/hip_runtime.h>
#include <hip/hip_bf16.h>
#include <cmath>

#define NROWS 32768
#define DIN   1024
#define DOUT  1024
#define BM    64
#define BK    32
#define NKT   (DIN / BK)   // 32 K-steps
#define MAXNORM 0.996f     // (1 - 4e-3)/sqrt(c), c = 1
#define XPAD  40           // Xt row = 80 B -> 2-way banks (free)

typedef __attribute__((ext_vector_type(8))) __bf16 bf16x8;
typedef __attribute__((ext_vector_type(4))) float  f32x4;

__device__ __forceinline__ void gload16(const void* g, void* l) {
    __builtin_amdgcn_global_load_lds(
        (const __attribute__((address_space(1))) void*)g,
        (__attribute__((address_space(3))) void*)l, 16, 0, 0);
}

__device__ __forceinline__ unsigned pack2bf(float a, float b) {
    union { unsigned u; __bf16 h[2]; } p;
    p.h[0] = (__bf16)a; p.h[1] = (__bf16)b;
    return p.u;
}

// Pre-swizzled, K-tile-major bf16 W in workspace.
// 16B chunk cid = [kt(5b)][n(10b)][q(2b)];
// content = W[n][kt*32 + (q ^ ((n>>1)&3))*8 .. +7].
// gload_lds streams chunks linearly into LDS; the XOR'd quarter placement
// makes the B ds_read_b128 (16 rows x 64B stride) hit all 32 banks evenly.
__global__ void conv_w_kernel(const float* __restrict__ Wf, __bf16* __restrict__ Wb) {
    int cid = blockIdx.x * blockDim.x + threadIdx.x;   // 131072 chunks
    int q   = cid & 3;
    int n   = (cid >> 2) & (DOUT - 1);
    int kt  = cid >> 12;
    int k0  = kt * BK + ((q ^ ((n >> 1) & 3)) << 3);
    const float* src = Wf + (size_t)n * DIN + k0;
    f32x4 v0 = *(const f32x4*)src;
    f32x4 v1 = *(const f32x4*)(src + 4);
    uint4 o;
    o.x = pack2bf(v0[0], v0[1]); o.y = pack2bf(v0[2], v0[3]);
    o.z = pack2bf(v1[0], v1[1]); o.w = pack2bf(v1[2], v1[3]);
    *(uint4*)((char*)Wb + (size_t)cid * 16) = o;
}

// Fused bf16 MFMA GEMM (x @ W^T) + hyperbolic epilogue.
// 8 waves, each owns a 64x128 output tile (full BM rows x 128 cols).
template<bool WBF>
__global__ __launch_bounds__(512, 2) void hyp_kernel(
    const float* __restrict__ X,
    const float* __restrict__ Wf,
    const __bf16* __restrict__ Wb,
    const float* __restrict__ bias,
    float* __restrict__ out)
{
    __shared__ __align__(16) __bf16 Wt[2][DOUT * BK];  // 2 x 64 KB, swizzled quarters
    __shared__ __align__(16) __bf16 Xt[2][BM * XPAD];  // 2 x 5 KB, padded rows
    __shared__ float hbs[DOUT];
    __shared__ float redq[BM][8];
    __shared__ float redd[BM][8];
    __shared__ float xsqs[BM];
    __shared__ float fco[BM][2];
    __shared__ float bred[8];

    const int tid  = threadIdx.x;
    const int lane = tid & 63;
    const int wid  = tid >> 6;       // 0..7 = column group (128 cols each)
    const int l15  = lane & 15;
    const int l4   = lane >> 4;
    const int row0 = blockIdx.x * BM;

    // x staging: thread -> (row, 4 k-elems)
    const int xr = tid >> 3;         // 0..63
    const int xk = (tid & 7) * 4;    // 0..28
    const float* xp = X + (size_t)(row0 + xr) * DIN + xk;
    float xsq = 0.f;

    f32x4 acc[4][8];
    #pragma unroll
    for (int m = 0; m < 4; m++)
        #pragma unroll
        for (int nt = 0; nt < 8; nt++)
            acc[m][nt] = (f32x4){0.f, 0.f, 0.f, 0.f};

    auto STAGE = [&](int buf, int kt) {
        if (kt < NKT) {
            if constexpr (WBF) {
                #pragma unroll
                for (int j = 0; j < 8; j++) {
                    int c = (j << 9) + tid;            // 4096 chunks of 16 B
                    gload16((const char*)Wb + (((size_t)kt << 12) + c) * 16,
                            (char*)(&Wt[buf][0]) + (((j << 9) + (wid << 6)) << 4));
                }
            } else {
                #pragma unroll
                for (int j = 0; j < 8; j++) {
                    int c = (j << 9) + tid;
                    int q = c & 3, n = c >> 2;
                    int k0 = kt * BK + ((q ^ ((n >> 1) & 3)) << 3);
                    const float* src = Wf + (size_t)n * DIN + k0;
                    f32x4 v0 = *(const f32x4*)src;
                    f32x4 v1 = *(const f32x4*)(src + 4);
                    uint4 o;
                    o.x = pack2bf(v0[0], v0[1]); o.y = pack2bf(v0[2], v0[3]);
                    o.z = pack2bf(v1[0], v1[1]); o.w = pack2bf(v1[2], v1[3]);
                    *(uint4*)((char*)(&Wt[buf][0]) + c * 16) = o;
                }
            }
            f32x4 xv = *(const f32x4*)(xp + kt * BK);
            xsq += xv[0]*xv[0] + xv[1]*xv[1] + xv[2]*xv[2] + xv[3]*xv[3];
            uint2 pk;
            pk.x = pack2bf(xv[0], xv[1]);
            pk.y = pack2bf(xv[2], xv[3]);
            *(uint2*)((char*)(&Xt[buf][0]) + xr * (XPAD * 2) + xk * 2) = pk;
        }
    };

    // ---- prologue: issue tile 0, overlap with hyp-bias compute ----
    STAGE(0, 0);

    float b0 = bias[tid], b1 = bias[tid + 512];
    float bs = b0 * b0 + b1 * b1;
    #pragma unroll
    for (int m = 1; m < 64; m <<= 1) bs += __shfl_xor(bs, m);
    if (lane == 0) bred[wid] = bs;
    __syncthreads();
    float tot = 0.f;
    #pragma unroll
    for (int i = 0; i < 8; i++) tot += bred[i];
    const float bnorm = sqrtf(fmaxf(tot, 1e-15f));
    const float bth   = tanhf(bnorm);               // ||expmap0(bias)||
    float sc0 = bth / bnorm;
    float hn  = bth;
    if (hn > MAXNORM) { sc0 *= MAXNORM / hn; hn = MAXNORM; }
    hbs[tid]       = sc0 * b0;
    hbs[tid + 512] = sc0 * b1;
    const float y2c = hn * hn;                      // ||hyp_bias||^2
    __syncthreads();                                // hbs ready; tile 0 drained

    float hv[8];
    #pragma unroll
    for (int nt = 0; nt < 8; nt++) hv[nt] = hbs[(wid << 7) + (nt << 4) + l15];

    // ---- K loop: double-buffered, stage-early, 1 barrier/step ----
    int cur = 0;
    for (int kt = 0; kt < NKT; kt++) {
        STAGE(cur ^ 1, kt + 1);
        const char* xb = (const char*)(&Xt[cur][0]);
        const char* wb = (const char*)(&Wt[cur][0]);
        bf16x8 a[4], b[8];
        #pragma unroll
        for (int m = 0; m < 4; m++)
            a[m] = *(const bf16x8*)(xb + ((m << 4) + l15) * (XPAD * 2) + (l4 << 4));
        #pragma unroll
        for (int nt = 0; nt < 8; nt++) {
            int n = (wid << 7) + (nt << 4) + l15;
            b[nt] = *(const bf16x8*)(wb + n * 64 + ((l4 ^ ((n >> 1) & 3)) << 4));
        }
        #pragma unroll
        for (int m = 0; m < 4; m++)
            #pragma unroll
            for (int nt = 0; nt < 8; nt++)
                acc[m][nt] = __builtin_amdgcn_mfma_f32_16x16x32_bf16(a[m], b[nt], acc[m][nt], 0, 0, 0);
        __syncthreads();
        cur ^= 1;
    }

    // ---- row reductions ----
    float xs = xsq;                                  // 8 threads per row
    #pragma unroll
    for (int m = 1; m < 8; m <<= 1) xs += __shfl_xor(xs, m);
    if ((tid & 7) == 0) xsqs[xr] = xs;

    #pragma unroll
    for (int m = 0; m < 4; m++) {
        #pragma unroll
        for (int r = 0; r < 4; r++) {
            float s = 0.f, d = 0.f;
            #pragma unroll
            for (int nt = 0; nt < 8; nt++) {
                float v = acc[m][nt][r];
                s += v * v;
                d += v * hv[nt];
            }
            #pragma unroll
            for (int mm = 1; mm < 16; mm <<= 1) {    // cols live in low 4 lane bits
                s += __shfl_xor(s, mm);
                d += __shfl_xor(d, mm);
            }
            if (l15 == 0) {
                int rl = (m << 4) + (l4 << 2) + r;
                redq[rl][wid] = s;
                redd[rl][wid] = d;
            }
        }
    }
    __syncthreads();

    // ---- per-row scalars (64 threads) ----
    if (tid < BM) {
        int r = tid;
        float sq = 0.f, dt = 0.f;
        #pragma unroll
        for (int w = 0; w < 8; w++) { sq += redq[r][w]; dt += redd[r][w]; }
        float sx     = xsqs[r];
        float xnorm  = sqrtf(fmaxf(sx, 1e-15f));
        float mxnorm = sqrtf(fmaxf(sq, 1e-15f));
        float u  = fminf(xnorm, 1.f - 1e-5f);        // artanh clip
        float tv = tanhf(mxnorm / xnorm * atanhf(u));
        float rn = fminf(tv, MAXNORM);               // project(res) norm
        float s  = rn / mxnorm;
        float xy = s * dt;
        float x2 = rn * rn;
        float Am = 1.f + 2.f * xy + y2c;
        float Bm = 1.f - x2;
        float Dm = fmaxf(1.f + 2.f * xy + x2 * y2c, 1e-15f);
        float g1 = Am * s / Dm;
        float g2 = Bm / Dm;
        float osq   = g1 * g1 * sq + 2.f * g1 * g2 * dt + g2 * g2 * y2c;
        float onorm = sqrtf(fmaxf(osq, 1e-15f));
        float psc   = onorm > MAXNORM ? MAXNORM / onorm : 1.f;
        fco[r][0] = g1 * psc;
        fco[r][1] = g2 * psc;
    }
    __syncthreads();

    // ---- epilogue write ----
    #pragma unroll
    for (int m = 0; m < 4; m++) {
        #pragma unroll
        for (int r = 0; r < 4; r++) {
            int rl = (m << 4) + (l4 << 2) + r;
            float F1 = fco[rl][0], F2 = fco[rl][1];
            float* orow = out + (size_t)(row0 + rl) * DOUT + (wid << 7);
            #pragma unroll
            for (int nt = 0; nt < 8; nt++)
                orow[(nt << 4) + l15] = F1 * acc[m][nt][r] + F2 * hv[nt];
        }
    }
}

extern "C" void kernel_launch(void* const* d_in, const int* in_sizes, int n_in,
                              void* d_out, int out_size, void* d_ws, size_t ws_size,
                              hipStream_t stream) {
    const float* X    = (const float*)d_in[0];
    const float* W    = (const float*)d_in[1];
    const float* bias = (const float*)d_in[2];
    float* out = (float*)d_out;

    const size_t wb_bytes = (size_t)DOUT * DIN * 2;
    if (ws_size >= wb_bytes) {
        __bf16* Wb = (__bf16*)d_ws;
        conv_w_kernel<<<dim3(DOUT * DIN / (16 * 256) * 2), dim3(256), 0, stream>>>(W, Wb);
        hyp_kernel<true><<<dim3(NROWS / BM), dim3(512), 0, stream>>>(X, W, Wb, bias, out);
    } else {
        hyp_kernel<false><<<dim3(NROWS / BM), dim3(512), 0, stream>>>(X, W, nullptr, bias, out);
    }
}

// Round 3
// 121.672 us; speedup vs baseline: 1.2225x; 1.1131x over previous
//
#include <hip/hip_runtime.h>
#include <hip/hip_bf16.h>
#include <cmath>

#define NROWS 32768
#define DIN   1024
#define DOUT  1024
#define BM    64
#define BK    32
#define NKT   (DIN / BK)   // 32 K-steps
#define MAXNORM 0.996f     // (1 - 4e-3)/sqrt(c), c = 1
#define XPAD  40           // Xt row = 80 B -> 2-way banks (free)

typedef __attribute__((ext_vector_type(8))) __bf16 bf16x8;
typedef __attribute__((ext_vector_type(4))) float  f32x4;

__device__ __forceinline__ void gload16(const void* g, void* l) {
    __builtin_amdgcn_global_load_lds(
        (const __attribute__((address_space(1))) void*)g,
        (__attribute__((address_space(3))) void*)l, 16, 0, 0);
}

__device__ __forceinline__ unsigned pack2bf(float a, float b) {
    union { unsigned u; __bf16 h[2]; } p;
    p.h[0] = (__bf16)a; p.h[1] = (__bf16)b;
    return p.u;
}

// counted-vmcnt wait + raw barrier: loads stay in flight across the barrier
#define WAITBAR(N) do {                                                   \
    asm volatile("s_waitcnt vmcnt(" #N ") lgkmcnt(0)" ::: "memory");      \
    __builtin_amdgcn_s_barrier();                                         \
    __builtin_amdgcn_sched_barrier(0);                                    \
} while (0)

// Workspace W layout: per (kt, h): 2048 chunks of 16B, chunk = [g2(5)][r(4)][q(2)]
// content = W[n][kt*32 + (q ^ ((r>>1)&3))*8 .. +7],  n = (g2*2 + h)*16 + r.
// h = column-16-group parity (even groups -> WtA, odd -> WtB).
__global__ void conv_w_kernel(const float* __restrict__ Wf, __bf16* __restrict__ Wb) {
    int cid = blockIdx.x * blockDim.x + threadIdx.x;   // 131072 chunks
    int q  = cid & 3;
    int r  = (cid >> 2) & 15;
    int g2 = (cid >> 6) & 31;
    int h  = (cid >> 11) & 1;
    int kt = cid >> 12;
    int n  = ((g2 << 1) + h) * 16 + r;
    int k0 = kt * BK + ((q ^ ((r >> 1) & 3)) << 3);
    const float* src = Wf + (size_t)n * DIN + k0;
    f32x4 v0 = *(const f32x4*)src;
    f32x4 v1 = *(const f32x4*)(src + 4);
    uint4 o;
    o.x = pack2bf(v0[0], v0[1]); o.y = pack2bf(v0[2], v0[3]);
    o.z = pack2bf(v1[0], v1[1]); o.w = pack2bf(v1[2], v1[3]);
    *(uint4*)((char*)Wb + (size_t)cid * 16) = o;
}

// Deep-pipelined fused kernel: 2 phases/K-step, counted vmcnt, raw s_barrier.
__global__ __launch_bounds__(512, 2) void hyp_kernel_pipe(
    const float* __restrict__ X,
    const __bf16* __restrict__ Wb,
    const float* __restrict__ bias,
    float* __restrict__ out)
{
    __shared__ __align__(16) __bf16 WtA[2][512 * BK];  // even 16-col groups, 2x32KB
    __shared__ __align__(16) __bf16 WtB[2][512 * BK];  // odd  16-col groups, 2x32KB
    __shared__ __align__(16) __bf16 Xt[2][BM * XPAD];
    __shared__ float hbs[DOUT];
    __shared__ float redq[BM][8];
    __shared__ float redd[BM][8];
    __shared__ float xsqs[BM];
    __shared__ float fco[BM][2];
    __shared__ float bred[8];

    const int tid  = threadIdx.x;
    const int lane = tid & 63;
    const int wid  = tid >> 6;       // 0..7 = 128-col group
    const int l15  = lane & 15;
    const int l4   = lane >> 4;
    const int row0 = blockIdx.x * BM;

    const int xr = tid >> 3;         // 0..63
    const int xk = (tid & 7) * 4;    // 0..28
    const float* xp = X + (size_t)(row0 + xr) * DIN + xk;
    float xsq = 0.f;

    f32x4 acc[4][8];
    #pragma unroll
    for (int m = 0; m < 4; m++)
        #pragma unroll
        for (int nt = 0; nt < 8; nt++)
            acc[m][nt] = (f32x4){0.f, 0.f, 0.f, 0.f};

    auto wsrc = [&](int kt, int h) -> const char* {
        return (const char*)Wb + (((size_t)kt * 2 + h) << 15);   // 32 KB per half
    };
    auto issueHalf = [&](const char* g, __bf16* lds) {
        #pragma unroll
        for (int j = 0; j < 4; j++) {
            int c = (j << 9) + tid;                              // 2048 chunks
            gload16(g + (size_t)c * 16,
                    (char*)lds + (((j << 9) + (wid << 6)) << 4));
        }
    };

    f32x4 xv;
    auto xload  = [&](int kt) { xv = *(const f32x4*)(xp + kt * BK); };
    auto xstage = [&](int dstbuf) {
        xsq += xv[0]*xv[0] + xv[1]*xv[1] + xv[2]*xv[2] + xv[3]*xv[3];
        uint2 pk;
        pk.x = pack2bf(xv[0], xv[1]);
        pk.y = pack2bf(xv[2], xv[3]);
        *(uint2*)((char*)(&Xt[dstbuf][0]) + xr * (XPAD * 2) + xk * 2) = pk;
    };

    bf16x8 afr[4];
    auto cmpA = [&](int buf) {           // even nt: loads a-frags too
        const char* xb = (const char*)(&Xt[buf][0]);
        const char* wb = (const char*)(&WtA[buf][0]);
        #pragma unroll
        for (int m = 0; m < 4; m++)
            afr[m] = *(const bf16x8*)(xb + ((m << 4) + l15) * (XPAD * 2) + (l4 << 4));
        bf16x8 b[4];
        #pragma unroll
        for (int i = 0; i < 4; i++) {
            int g2 = (wid << 2) + i;
            b[i] = *(const bf16x8*)(wb + (((g2 << 6) + (l15 << 2) + (l4 ^ ((l15 >> 1) & 3))) << 4));
        }
        __builtin_amdgcn_s_setprio(1);
        #pragma unroll
        for (int i = 0; i < 4; i++)
            #pragma unroll
            for (int m = 0; m < 4; m++)
                acc[m][i * 2] = __builtin_amdgcn_mfma_f32_16x16x32_bf16(afr[m], b[i], acc[m][i * 2], 0, 0, 0);
        __builtin_amdgcn_s_setprio(0);
    };
    auto cmpB = [&](int buf) {           // odd nt: reuses a-frags
        const char* wb = (const char*)(&WtB[buf][0]);
        bf16x8 b[4];
        #pragma unroll
        for (int i = 0; i < 4; i++) {
            int g2 = (wid << 2) + i;
            b[i] = *(const bf16x8*)(wb + (((g2 << 6) + (l15 << 2) + (l4 ^ ((l15 >> 1) & 3))) << 4));
        }
        __builtin_amdgcn_s_setprio(1);
        #pragma unroll
        for (int i = 0; i < 4; i++)
            #pragma unroll
            for (int m = 0; m < 4; m++)
                acc[m][i * 2 + 1] = __builtin_amdgcn_mfma_f32_16x16x32_bf16(afr[m], b[i], acc[m][i * 2 + 1], 0, 0, 0);
        __builtin_amdgcn_s_setprio(0);
    };

    // ---- prologue: issue tile 0, overlap with hyp-bias compute ----
    issueHalf(wsrc(0, 0), &WtA[0][0]);
    issueHalf(wsrc(0, 1), &WtB[0][0]);
    xload(0);

    float b0 = bias[tid], b1 = bias[tid + 512];
    float bs = b0 * b0 + b1 * b1;
    #pragma unroll
    for (int m = 1; m < 64; m <<= 1) bs += __shfl_xor(bs, m);
    if (lane == 0) bred[wid] = bs;
    __syncthreads();
    float tot = 0.f;
    #pragma unroll
    for (int i = 0; i < 8; i++) tot += bred[i];
    const float bnorm = sqrtf(fmaxf(tot, 1e-15f));
    const float bth   = tanhf(bnorm);               // ||expmap0(bias)||
    float sc0 = bth / bnorm;
    float hn  = bth;
    if (hn > MAXNORM) { sc0 *= MAXNORM / hn; hn = MAXNORM; }
    hbs[tid]       = sc0 * b0;
    hbs[tid + 512] = sc0 * b1;
    const float y2c = hn * hn;                      // ||hyp_bias||^2
    __syncthreads();                                // also drains tile-0 loads

    float hv[8];
    #pragma unroll
    for (int nt = 0; nt < 8; nt++) hv[nt] = hbs[(wid << 7) + (nt << 4) + l15];

    xstage(0);                                      // Xt[0] <- x(0)
    xload(1);

    // ---- K loop: 2 phases/step, each half issued one full step ahead ----
    // phaseA(kt): issueA(kt+1); WAIT; BAR; cmpA(kt)
    // phaseB(kt): xwrite(kt+1); xload(kt+2); issueB(kt+1); WAIT; BAR; cmpB(kt)
    for (int kt = 0; kt < 30; kt += 2) {
        issueHalf(wsrc(kt + 1, 0), &WtA[1][0]); WAITBAR(9); cmpA(0);
        xstage(1); xload(kt + 2);
        issueHalf(wsrc(kt + 1, 1), &WtB[1][0]); WAITBAR(9); cmpB(0);

        issueHalf(wsrc(kt + 2, 0), &WtA[0][0]); WAITBAR(9); cmpA(1);
        xstage(0); xload(kt + 3);
        issueHalf(wsrc(kt + 2, 1), &WtB[0][0]); WAITBAR(9); cmpB(1);
    }
    // kt = 30 (buf 0)
    issueHalf(wsrc(31, 0), &WtA[1][0]); WAITBAR(9); cmpA(0);
    xstage(1);
    issueHalf(wsrc(31, 1), &WtB[1][0]); WAITBAR(8); cmpB(0);
    // kt = 31 (buf 1)
    WAITBAR(4); cmpA(1);
    WAITBAR(0); cmpB(1);

    // ---- row reductions ----
    float xs = xsq;                                  // 8 threads per row
    #pragma unroll
    for (int m = 1; m < 8; m <<= 1) xs += __shfl_xor(xs, m);
    if ((tid & 7) == 0) xsqs[xr] = xs;

    #pragma unroll
    for (int m = 0; m < 4; m++) {
        #pragma unroll
        for (int r = 0; r < 4; r++) {
            float s = 0.f, d = 0.f;
            #pragma unroll
            for (int nt = 0; nt < 8; nt++) {
                float v = acc[m][nt][r];
                s += v * v;
                d += v * hv[nt];
            }
            #pragma unroll
            for (int mm = 1; mm < 16; mm <<= 1) {    // cols live in low 4 lane bits
                s += __shfl_xor(s, mm);
                d += __shfl_xor(d, mm);
            }
            if (l15 == 0) {
                int rl = (m << 4) + (l4 << 2) + r;
                redq[rl][wid] = s;
                redd[rl][wid] = d;
            }
        }
    }
    __syncthreads();

    // ---- per-row scalars (64 threads) ----
    if (tid < BM) {
        int r = tid;
        float sq = 0.f, dt = 0.f;
        #pragma unroll
        for (int w = 0; w < 8; w++) { sq += redq[r][w]; dt += redd[r][w]; }
        float sx     = xsqs[r];
        float xnorm  = sqrtf(fmaxf(sx, 1e-15f));
        float mxnorm = sqrtf(fmaxf(sq, 1e-15f));
        float u  = fminf(xnorm, 1.f - 1e-5f);        // artanh clip
        float tv = tanhf(mxnorm / xnorm * atanhf(u));
        float rn = fminf(tv, MAXNORM);               // project(res) norm
        float s  = rn / mxnorm;
        float xy = s * dt;
        float x2 = rn * rn;
        float Am = 1.f + 2.f * xy + y2c;
        float Bm = 1.f - x2;
        float Dm = fmaxf(1.f + 2.f * xy + x2 * y2c, 1e-15f);
        float g1 = Am * s / Dm;
        float g2 = Bm / Dm;
        float osq   = g1 * g1 * sq + 2.f * g1 * g2 * dt + g2 * g2 * y2c;
        float onorm = sqrtf(fmaxf(osq, 1e-15f));
        float psc   = onorm > MAXNORM ? MAXNORM / onorm : 1.f;
        fco[r][0] = g1 * psc;
        fco[r][1] = g2 * psc;
    }
    __syncthreads();

    // ---- epilogue write ----
    #pragma unroll
    for (int m = 0; m < 4; m++) {
        #pragma unroll
        for (int r = 0; r < 4; r++) {
            int rl = (m << 4) + (l4 << 2) + r;
            float F1 = fco[rl][0], F2 = fco[rl][1];
            float* orow = out + (size_t)(row0 + rl) * DOUT + (wid << 7);
            #pragma unroll
            for (int nt = 0; nt < 8; nt++)
                orow[(nt << 4) + l15] = F1 * acc[m][nt][r] + F2 * hv[nt];
        }
    }
}

// Fallback (ws too small): round-2 verified structure, manual W pack, __syncthreads.
__global__ __launch_bounds__(512, 2) void hyp_kernel_basic(
    const float* __restrict__ X,
    const float* __restrict__ Wf,
    const float* __restrict__ bias,
    float* __restrict__ out)
{
    __shared__ __align__(16) __bf16 Wt[2][DOUT * BK];
    __shared__ __align__(16) __bf16 Xt[2][BM * XPAD];
    __shared__ float hbs[DOUT];
    __shared__ float redq[BM][8];
    __shared__ float redd[BM][8];
    __shared__ float xsqs[BM];
    __shared__ float fco[BM][2];
    __shared__ float bred[8];

    const int tid  = threadIdx.x;
    const int lane = tid & 63;
    const int wid  = tid >> 6;
    const int l15  = lane & 15;
    const int l4   = lane >> 4;
    const int row0 = blockIdx.x * BM;
    const int xr = tid >> 3;
    const int xk = (tid & 7) * 4;
    const float* xp = X + (size_t)(row0 + xr) * DIN + xk;
    float xsq = 0.f;

    f32x4 acc[4][8];
    #pragma unroll
    for (int m = 0; m < 4; m++)
        #pragma unroll
        for (int nt = 0; nt < 8; nt++)
            acc[m][nt] = (f32x4){0.f, 0.f, 0.f, 0.f};

    auto STAGE = [&](int buf, int kt) {
        if (kt < NKT) {
            #pragma unroll
            for (int j = 0; j < 8; j++) {
                int c = (j << 9) + tid;
                int q = c & 3, n = c >> 2;
                int k0 = kt * BK + ((q ^ ((n >> 1) & 3)) << 3);
                const float* src = Wf + (size_t)n * DIN + k0;
                f32x4 v0 = *(const f32x4*)src;
                f32x4 v1 = *(const f32x4*)(src + 4);
                uint4 o;
                o.x = pack2bf(v0[0], v0[1]); o.y = pack2bf(v0[2], v0[3]);
                o.z = pack2bf(v1[0], v1[1]); o.w = pack2bf(v1[2], v1[3]);
                *(uint4*)((char*)(&Wt[buf][0]) + c * 16) = o;
            }
            f32x4 xv = *(const f32x4*)(xp + kt * BK);
            xsq += xv[0]*xv[0] + xv[1]*xv[1] + xv[2]*xv[2] + xv[3]*xv[3];
            uint2 pk;
            pk.x = pack2bf(xv[0], xv[1]);
            pk.y = pack2bf(xv[2], xv[3]);
            *(uint2*)((char*)(&Xt[buf][0]) + xr * (XPAD * 2) + xk * 2) = pk;
        }
    };

    STAGE(0, 0);

    float b0 = bias[tid], b1 = bias[tid + 512];
    float bs = b0 * b0 + b1 * b1;
    #pragma unroll
    for (int m = 1; m < 64; m <<= 1) bs += __shfl_xor(bs, m);
    if (lane == 0) bred[wid] = bs;
    __syncthreads();
    float tot = 0.f;
    #pragma unroll
    for (int i = 0; i < 8; i++) tot += bred[i];
    const float bnorm = sqrtf(fmaxf(tot, 1e-15f));
    const float bth   = tanhf(bnorm);
    float sc0 = bth / bnorm;
    float hn  = bth;
    if (hn > MAXNORM) { sc0 *= MAXNORM / hn; hn = MAXNORM; }
    hbs[tid]       = sc0 * b0;
    hbs[tid + 512] = sc0 * b1;
    const float y2c = hn * hn;
    __syncthreads();

    float hv[8];
    #pragma unroll
    for (int nt = 0; nt < 8; nt++) hv[nt] = hbs[(wid << 7) + (nt << 4) + l15];

    int cur = 0;
    for (int kt = 0; kt < NKT; kt++) {
        STAGE(cur ^ 1, kt + 1);
        const char* xb = (const char*)(&Xt[cur][0]);
        const char* wb = (const char*)(&Wt[cur][0]);
        bf16x8 a[4], b[8];
        #pragma unroll
        for (int m = 0; m < 4; m++)
            a[m] = *(const bf16x8*)(xb + ((m << 4) + l15) * (XPAD * 2) + (l4 << 4));
        #pragma unroll
        for (int nt = 0; nt < 8; nt++) {
            int n = (wid << 7) + (nt << 4) + l15;
            b[nt] = *(const bf16x8*)(wb + n * 64 + ((l4 ^ ((n >> 1) & 3)) << 4));
        }
        #pragma unroll
        for (int m = 0; m < 4; m++)
            #pragma unroll
            for (int nt = 0; nt < 8; nt++)
                acc[m][nt] = __builtin_amdgcn_mfma_f32_16x16x32_bf16(a[m], b[nt], acc[m][nt], 0, 0, 0);
        __syncthreads();
        cur ^= 1;
    }

    float xs = xsq;
    #pragma unroll
    for (int m = 1; m < 8; m <<= 1) xs += __shfl_xor(xs, m);
    if ((tid & 7) == 0) xsqs[xr] = xs;

    #pragma unroll
    for (int m = 0; m < 4; m++) {
        #pragma unroll
        for (int r = 0; r < 4; r++) {
            float s = 0.f, d = 0.f;
            #pragma unroll
            for (int nt = 0; nt < 8; nt++) {
                float v = acc[m][nt][r];
                s += v * v;
                d += v * hv[nt];
            }
            #pragma unroll
            for (int mm = 1; mm < 16; mm <<= 1) {
                s += __shfl_xor(s, mm);
                d += __shfl_xor(d, mm);
            }
            if (l15 == 0) {
                int rl = (m << 4) + (l4 << 2) + r;
                redq[rl][wid] = s;
                redd[rl][wid] = d;
            }
        }
    }
    __syncthreads();

    if (tid < BM) {
        int r = tid;
        float sq = 0.f, dt = 0.f;
        #pragma unroll
        for (int w = 0; w < 8; w++) { sq += redq[r][w]; dt += redd[r][w]; }
        float sx     = xsqs[r];
        float xnorm  = sqrtf(fmaxf(sx, 1e-15f));
        float mxnorm = sqrtf(fmaxf(sq, 1e-15f));
        float u  = fminf(xnorm, 1.f - 1e-5f);
        float tv = tanhf(mxnorm / xnorm * atanhf(u));
        float rn = fminf(tv, MAXNORM);
        float s  = rn / mxnorm;
        float xy = s * dt;
        float x2 = rn * rn;
        float Am = 1.f + 2.f * xy + y2c;
        float Bm = 1.f - x2;
        float Dm = fmaxf(1.f + 2.f * xy + x2 * y2c, 1e-15f);
        float g1 = Am * s / Dm;
        float g2 = Bm / Dm;
        float osq   = g1 * g1 * sq + 2.f * g1 * g2 * dt + g2 * g2 * y2c;
        float onorm = sqrtf(fmaxf(osq, 1e-15f));
        float psc   = onorm > MAXNORM ? MAXNORM / onorm : 1.f;
        fco[r][0] = g1 * psc;
        fco[r][1] = g2 * psc;
    }
    __syncthreads();

    #pragma unroll
    for (int m = 0; m < 4; m++) {
        #pragma unroll
        for (int r = 0; r < 4; r++) {
            int rl = (m << 4) + (l4 << 2) + r;
            float F1 = fco[rl][0], F2 = fco[rl][1];
            float* orow = out + (size_t)(row0 + rl) * DOUT + (wid << 7);
            #pragma unroll
            for (int nt = 0; nt < 8; nt++)
                orow[(nt << 4) + l15] = F1 * acc[m][nt][r] + F2 * hv[nt];
        }
    }
}

extern "C" void kernel_launch(void* const* d_in, const int* in_sizes, int n_in,
                              void* d_out, int out_size, void* d_ws, size_t ws_size,
                              hipStream_t stream) {
    const float* X    = (const float*)d_in[0];
    const float* W    = (const float*)d_in[1];
    const float* bias = (const float*)d_in[2];
    float* out = (float*)d_out;

    const size_t wb_bytes = (size_t)DOUT * DIN * 2;
    if (ws_size >= wb_bytes) {
        __bf16* Wb = (__bf16*)d_ws;
        conv_w_kernel<<<dim3(512), dim3(256), 0, stream>>>(W, Wb);
        hyp_kernel_pipe<<<dim3(NROWS / BM), dim3(512), 0, stream>>>(X, Wb, bias, out);
    } else {
        hyp_kernel_basic<<<dim3(NROWS / BM), dim3(512), 0, stream>>>(X, W, bias, out);
    }
}

// Round 4
// 112.121 us; speedup vs baseline: 1.3267x; 1.0852x over previous
//
#include <hip/hip_runtime.h>
#include <hip/hip_bf16.h>
#include <cmath>

#define NROWS 32768
#define DIN   1024
#define DOUT  1024
#define BM    64
#define BK    32
#define NKT   (DIN / BK)   // 32 K-steps
#define MAXNORM 0.996f     // (1 - 4e-3)/sqrt(c), c = 1
#define XPAD  40           // Xt row = 80 B -> 2-way banks (free)

typedef __attribute__((ext_vector_type(8))) __bf16 bf16x8;
typedef __attribute__((ext_vector_type(4))) float  f32x4;

__device__ __forceinline__ unsigned pack2bf(float a, float b) {
    union { unsigned u; __bf16 h[2]; } p;
    p.h[0] = (__bf16)a; p.h[1] = (__bf16)b;
    return p.u;
}

// Fragment-ordered bf16 W pack: 16B chunk c = [kt(5)][j(6)][lane(6)],
// content = W[n][k0..k0+8) with n = j*16 + (lane&15), k0 = kt*32 + (lane>>4)*8.
// A wave's B-frag load (j = wid*4+i) is then base + lane*16: one fully
// coalesced 1KB global_load_dwordx4 per fragment, straight to VGPRs.
__global__ void conv_w_kernel(const float* __restrict__ Wf, __bf16* __restrict__ Wb) {
    int c  = blockIdx.x * blockDim.x + threadIdx.x;   // 131072 chunks
    int l  = c & 63;
    int j  = (c >> 6) & 63;
    int kt = c >> 12;
    int n  = j * 16 + (l & 15);
    int k0 = kt * 32 + (l >> 4) * 8;
    const float* src = Wf + (size_t)n * DIN + k0;
    f32x4 v0 = *(const f32x4*)src;
    f32x4 v1 = *(const f32x4*)(src + 4);
    uint4 o;
    o.x = pack2bf(v0[0], v0[1]); o.y = pack2bf(v0[2], v0[3]);
    o.z = pack2bf(v1[0], v1[1]); o.w = pack2bf(v1[2], v1[3]);
    *(uint4*)((char*)Wb + (size_t)c * 16) = o;
}

// Fused bf16 MFMA GEMM (x @ W^T) + hyperbolic epilogue.
// 16 waves of 64r x 64c; W straight global->VGPR (no LDS); X via 3-buf LDS ring,
// one raw barrier + lgkmcnt(0) per K-step (W/X loads stay in flight across it).
__global__ __launch_bounds__(1024) void hyp_kernel_reg(
    const float* __restrict__ X,
    const __bf16* __restrict__ Wb,
    const float* __restrict__ bias,
    float* __restrict__ out)
{
    __shared__ __align__(16) __bf16 Xt[3][BM * XPAD];   // 15360 B ring
    __shared__ float hbs[DOUT];
    __shared__ float xsqs[BM];
    __shared__ float fco[BM][2];
    __shared__ float bred[16];

    const int tid  = threadIdx.x;
    const int lane = tid & 63;
    const int wid  = tid >> 6;       // 0..15 = 64-col group
    const int l15  = lane & 15;
    const int l4   = lane >> 4;
    const int row0 = blockIdx.x * BM;

    // x staging: thread -> (row, k-pair)
    const int xr = tid >> 4;         // 0..63
    const int xk = (tid & 15) * 2;   // 0..30
    const float* xp = X + (size_t)(row0 + xr) * DIN + xk;
    float xsq = 0.f;

    // per-wave W fragment base (elements); frag i at +i*512, K-step at +32768
    const __bf16* wp = Wb + ((size_t)(wid * 4) * 64 + lane) * 8;

    f32x4 acc[4][4];
    #pragma unroll
    for (int m = 0; m < 4; m++)
        #pragma unroll
        for (int n = 0; n < 4; n++)
            acc[m][n] = (f32x4){0.f, 0.f, 0.f, 0.f};

    // ---- prologue: issue first loads, overlap with hyp-bias compute ----
    float2 xw = *(const float2*)xp;            // tile 0
    float2 xf = *(const float2*)(xp + BK);     // tile 1
    bf16x8 bfr[4];
    #pragma unroll
    for (int i = 0; i < 4; i++) bfr[i] = *(const bf16x8*)(wp + i * 512);  // W(0)

    float bv = bias[tid];
    float bs = bv * bv;
    #pragma unroll
    for (int m = 1; m < 64; m <<= 1) bs += __shfl_xor(bs, m);
    if (lane == 0) bred[wid] = bs;
    __syncthreads();
    float tot = 0.f;
    #pragma unroll
    for (int i = 0; i < 16; i++) tot += bred[i];
    const float bnorm = sqrtf(fmaxf(tot, 1e-15f));
    const float bth   = tanhf(bnorm);          // ||expmap0(bias)||
    float sc0 = bth / bnorm;
    float hn  = bth;
    if (hn > MAXNORM) { sc0 *= MAXNORM / hn; hn = MAXNORM; }
    hbs[tid] = sc0 * bv;
    const float y2c = hn * hn;                 // ||hyp_bias||^2

    // stage tile 0 (xw landed: the __syncthreads above drained vmcnt)
    xsq += xw.x * xw.x + xw.y * xw.y;
    *(unsigned*)((char*)(&Xt[0][0]) + xr * (XPAD * 2) + xk * 2) = pack2bf(xw.x, xw.y);
    xw = xf;
    xf = *(const float2*)(xp + 2 * BK);        // tile 2

    // ---- K loop: 1 raw barrier/step; vmcnt never force-drained ----
    int br = 0, bw = 1;                        // read buf = kt%3, write buf = (kt+1)%3
    for (int kt = 0; kt < NKT; kt++) {
        if (kt + 1 < NKT) {                    // stage tile kt+1 (exactly NKT stages total)
            xsq += xw.x * xw.x + xw.y * xw.y;
            *(unsigned*)((char*)(&Xt[bw][0]) + xr * (XPAD * 2) + xk * 2) = pack2bf(xw.x, xw.y);
        }
        xw = xf;
        int xt = kt + 3 < NKT ? kt + 3 : NKT - 1;
        xf = *(const float2*)(xp + (size_t)xt * BK);   // HBM, ~2 steps of flight

        asm volatile("s_waitcnt lgkmcnt(0)" ::: "memory");  // ds_writes visible
        __builtin_amdgcn_s_barrier();
        __builtin_amdgcn_sched_barrier(0);

        bf16x8 a[4];
        const char* xb = (const char*)(&Xt[br][0]);
        #pragma unroll
        for (int m = 0; m < 4; m++)
            a[m] = *(const bf16x8*)(xb + ((m << 4) + l15) * (XPAD * 2) + (l4 << 4));

        __builtin_amdgcn_s_setprio(1);
        #pragma unroll
        for (int n = 0; n < 4; n++)
            #pragma unroll
            for (int m = 0; m < 4; m++)
                acc[m][n] = __builtin_amdgcn_mfma_f32_16x16x32_bf16(a[m], bfr[n], acc[m][n], 0, 0, 0);
        __builtin_amdgcn_s_setprio(0);

        int ktb = kt + 1 < NKT ? kt + 1 : NKT - 1;     // W(kt+1), L2-resident
        const __bf16* wkp = wp + (size_t)ktb * 32768;
        #pragma unroll
        for (int i = 0; i < 4; i++) bfr[i] = *(const bf16x8*)(wkp + i * 512);

        br = br + 1 == 3 ? 0 : br + 1;
        bw = bw + 1 == 3 ? 0 : bw + 1;
    }

    __syncthreads();                            // loop done; full drain OK now

    // ---- row reductions (redq/redd alias the dead Xt ring) ----
    float* redq = (float*)(&Xt[0][0]);          // [64][16]
    float* redd = redq + BM * 16;               // 8 KB total <= 15360

    float xs = xsq;                             // 16 threads per row
    #pragma unroll
    for (int m = 1; m < 16; m <<= 1) xs += __shfl_xor(xs, m);
    if (l15 == 0) xsqs[xr] = xs;

    float hv[4];
    #pragma unroll
    for (int n = 0; n < 4; n++) hv[n] = hbs[(wid << 6) + (n << 4) + l15];

    #pragma unroll
    for (int m = 0; m < 4; m++) {
        #pragma unroll
        for (int r = 0; r < 4; r++) {
            float s = 0.f, d = 0.f;
            #pragma unroll
            for (int n = 0; n < 4; n++) {
                float v = acc[m][n][r];
                s += v * v;
                d += v * hv[n];
            }
            #pragma unroll
            for (int mm = 1; mm < 16; mm <<= 1) {   // cols live in low 4 lane bits
                s += __shfl_xor(s, mm);
                d += __shfl_xor(d, mm);
            }
            if (l15 == 0) {
                int rl = (m << 4) + (l4 << 2) + r;
                redq[rl * 16 + wid] = s;
                redd[rl * 16 + wid] = d;
            }
        }
    }
    __syncthreads();

    // ---- per-row scalars (64 threads) ----
    if (tid < BM) {
        int r = tid;
        float sq = 0.f, dt = 0.f;
        #pragma unroll
        for (int w = 0; w < 16; w++) { sq += redq[r * 16 + w]; dt += redd[r * 16 + w]; }
        float sx     = xsqs[r];
        float xnorm  = sqrtf(fmaxf(sx, 1e-15f));
        float mxnorm = sqrtf(fmaxf(sq, 1e-15f));
        float u  = fminf(xnorm, 1.f - 1e-5f);   // artanh clip
        float tv = tanhf(mxnorm / xnorm * atanhf(u));
        float rn = fminf(tv, MAXNORM);          // project(res) norm
        float s  = rn / mxnorm;
        float xy = s * dt;
        float x2 = rn * rn;
        float Am = 1.f + 2.f * xy + y2c;
        float Bm = 1.f - x2;
        float Dm = fmaxf(1.f + 2.f * xy + x2 * y2c, 1e-15f);
        float g1 = Am * s / Dm;
        float g2 = Bm / Dm;
        float osq   = g1 * g1 * sq + 2.f * g1 * g2 * dt + g2 * g2 * y2c;
        float onorm = sqrtf(fmaxf(osq, 1e-15f));
        float psc   = onorm > MAXNORM ? MAXNORM / onorm : 1.f;
        fco[r][0] = g1 * psc;
        fco[r][1] = g2 * psc;
    }
    __syncthreads();

    // ---- epilogue write ----
    #pragma unroll
    for (int m = 0; m < 4; m++) {
        #pragma unroll
        for (int r = 0; r < 4; r++) {
            int rl = (m << 4) + (l4 << 2) + r;
            float F1 = fco[rl][0], F2 = fco[rl][1];
            float* orow = out + (size_t)(row0 + rl) * DOUT + (wid << 6);
            #pragma unroll
            for (int n = 0; n < 4; n++)
                orow[(n << 4) + l15] = F1 * acc[m][n][r] + F2 * hv[n];
        }
    }
}

// Fallback (ws too small): round-2 verified structure, manual W pack, __syncthreads.
__global__ __launch_bounds__(512, 2) void hyp_kernel_basic(
    const float* __restrict__ X,
    const float* __restrict__ Wf,
    const float* __restrict__ bias,
    float* __restrict__ out)
{
    __shared__ __align__(16) __bf16 Wt[2][DOUT * BK];
    __shared__ __align__(16) __bf16 Xt[2][BM * XPAD];
    __shared__ float hbs[DOUT];
    __shared__ float redq[BM][8];
    __shared__ float redd[BM][8];
    __shared__ float xsqs[BM];
    __shared__ float fco[BM][2];
    __shared__ float bred[8];

    const int tid  = threadIdx.x;
    const int lane = tid & 63;
    const int wid  = tid >> 6;
    const int l15  = lane & 15;
    const int l4   = lane >> 4;
    const int row0 = blockIdx.x * BM;
    const int xr = tid >> 3;
    const int xk = (tid & 7) * 4;
    const float* xp = X + (size_t)(row0 + xr) * DIN + xk;
    float xsq = 0.f;

    f32x4 acc[4][8];
    #pragma unroll
    for (int m = 0; m < 4; m++)
        #pragma unroll
        for (int nt = 0; nt < 8; nt++)
            acc[m][nt] = (f32x4){0.f, 0.f, 0.f, 0.f};

    auto STAGE = [&](int buf, int kt) {
        if (kt < NKT) {
            #pragma unroll
            for (int j = 0; j < 8; j++) {
                int c = (j << 9) + tid;
                int q = c & 3, n = c >> 2;
                int k0 = kt * BK + ((q ^ ((n >> 1) & 3)) << 3);
                const float* src = Wf + (size_t)n * DIN + k0;
                f32x4 v0 = *(const f32x4*)src;
                f32x4 v1 = *(const f32x4*)(src + 4);
                uint4 o;
                o.x = pack2bf(v0[0], v0[1]); o.y = pack2bf(v0[2], v0[3]);
                o.z = pack2bf(v1[0], v1[1]); o.w = pack2bf(v1[2], v1[3]);
                *(uint4*)((char*)(&Wt[buf][0]) + c * 16) = o;
            }
            f32x4 xv = *(const f32x4*)(xp + kt * BK);
            xsq += xv[0]*xv[0] + xv[1]*xv[1] + xv[2]*xv[2] + xv[3]*xv[3];
            uint2 pk;
            pk.x = pack2bf(xv[0], xv[1]);
            pk.y = pack2bf(xv[2], xv[3]);
            *(uint2*)((char*)(&Xt[buf][0]) + xr * (XPAD * 2) + xk * 2) = pk;
        }
    };

    STAGE(0, 0);

    float b0 = bias[tid], b1 = bias[tid + 512];
    float bs = b0 * b0 + b1 * b1;
    #pragma unroll
    for (int m = 1; m < 64; m <<= 1) bs += __shfl_xor(bs, m);
    if (lane == 0) bred[wid] = bs;
    __syncthreads();
    float tot = 0.f;
    #pragma unroll
    for (int i = 0; i < 8; i++) tot += bred[i];
    const float bnorm = sqrtf(fmaxf(tot, 1e-15f));
    const float bth   = tanhf(bnorm);
    float sc0 = bth / bnorm;
    float hn  = bth;
    if (hn > MAXNORM) { sc0 *= MAXNORM / hn; hn = MAXNORM; }
    hbs[tid]       = sc0 * b0;
    hbs[tid + 512] = sc0 * b1;
    const float y2c = hn * hn;
    __syncthreads();

    float hv[8];
    #pragma unroll
    for (int nt = 0; nt < 8; nt++) hv[nt] = hbs[(wid << 7) + (nt << 4) + l15];

    int cur = 0;
    for (int kt = 0; kt < NKT; kt++) {
        STAGE(cur ^ 1, kt + 1);
        const char* xb = (const char*)(&Xt[cur][0]);
        const char* wb = (const char*)(&Wt[cur][0]);
        bf16x8 a[4], b[8];
        #pragma unroll
        for (int m = 0; m < 4; m++)
            a[m] = *(const bf16x8*)(xb + ((m << 4) + l15) * (XPAD * 2) + (l4 << 4));
        #pragma unroll
        for (int nt = 0; nt < 8; nt++) {
            int n = (wid << 7) + (nt << 4) + l15;
            b[nt] = *(const bf16x8*)(wb + n * 64 + ((l4 ^ ((n >> 1) & 3)) << 4));
        }
        #pragma unroll
        for (int m = 0; m < 4; m++)
            #pragma unroll
            for (int nt = 0; nt < 8; nt++)
                acc[m][nt] = __builtin_amdgcn_mfma_f32_16x16x32_bf16(a[m], b[nt], acc[m][nt], 0, 0, 0);
        __syncthreads();
        cur ^= 1;
    }

    float xs = xsq;
    #pragma unroll
    for (int m = 1; m < 8; m <<= 1) xs += __shfl_xor(xs, m);
    if ((tid & 7) == 0) xsqs[xr] = xs;

    #pragma unroll
    for (int m = 0; m < 4; m++) {
        #pragma unroll
        for (int r = 0; r < 4; r++) {
            float s = 0.f, d = 0.f;
            #pragma unroll
            for (int nt = 0; nt < 8; nt++) {
                float v = acc[m][nt][r];
                s += v * v;
                d += v * hv[nt];
            }
            #pragma unroll
            for (int mm = 1; mm < 16; mm <<= 1) {
                s += __shfl_xor(s, mm);
                d += __shfl_xor(d, mm);
            }
            if (l15 == 0) {
                int rl = (m << 4) + (l4 << 2) + r;
                redq[rl][wid] = s;
                redd[rl][wid] = d;
            }
        }
    }
    __syncthreads();

    if (tid < BM) {
        int r = tid;
        float sq = 0.f, dt = 0.f;
        #pragma unroll
        for (int w = 0; w < 8; w++) { sq += redq[r][w]; dt += redd[r][w]; }
        float sx     = xsqs[r];
        float xnorm  = sqrtf(fmaxf(sx, 1e-15f));
        float mxnorm = sqrtf(fmaxf(sq, 1e-15f));
        float u  = fminf(xnorm, 1.f - 1e-5f);
        float tv = tanhf(mxnorm / xnorm * atanhf(u));
        float rn = fminf(tv, MAXNORM);
        float s  = rn / mxnorm;
        float xy = s * dt;
        float x2 = rn * rn;
        float Am = 1.f + 2.f * xy + y2c;
        float Bm = 1.f - x2;
        float Dm = fmaxf(1.f + 2.f * xy + x2 * y2c, 1e-15f);
        float g1 = Am * s / Dm;
        float g2 = Bm / Dm;
        float osq   = g1 * g1 * sq + 2.f * g1 * g2 * dt + g2 * g2 * y2c;
        float onorm = sqrtf(fmaxf(osq, 1e-15f));
        float psc   = onorm > MAXNORM ? MAXNORM / onorm : 1.f;
        fco[r][0] = g1 * psc;
        fco[r][1] = g2 * psc;
    }
    __syncthreads();

    #pragma unroll
    for (int m = 0; m < 4; m++) {
        #pragma unroll
        for (int r = 0; r < 4; r++) {
            int rl = (m << 4) + (l4 << 2) + r;
            float F1 = fco[rl][0], F2 = fco[rl][1];
            float* orow = out + (size_t)(row0 + rl) * DOUT + (wid << 7);
            #pragma unroll
            for (int nt = 0; nt < 8; nt++)
                orow[(nt << 4) + l15] = F1 * acc[m][nt][r] + F2 * hv[nt];
        }
    }
}

extern "C" void kernel_launch(void* const* d_in, const int* in_sizes, int n_in,
                              void* d_out, int out_size, void* d_ws, size_t ws_size,
                              hipStream_t stream) {
    const float* X    = (const float*)d_in[0];
    const float* W    = (const float*)d_in[1];
    const float* bias = (const float*)d_in[2];
    float* out = (float*)d_out;

    const size_t wb_bytes = (size_t)DOUT * DIN * 2;
    if (ws_size >= wb_bytes) {
        __bf16* Wb = (__bf16*)d_ws;
        conv_w_kernel<<<dim3(512), dim3(256), 0, stream>>>(W, Wb);
        hyp_kernel_reg<<<dim3(NROWS / BM), dim3(1024), 0, stream>>>(X, Wb, bias, out);
    } else {
        hyp_kernel_basic<<<dim3(NROWS / BM), dim3(512), 0, stream>>>(X, W, bias, out);
    }
}